// Round 10
// baseline (379.971 us; speedup 1.0000x reference)
//
#include <hip/hip_runtime.h>
#include <math.h>

typedef __bf16 bf16_t;
typedef __bf16 bf16x8 __attribute__((ext_vector_type(8)));
typedef __bf16 bf16x4 __attribute__((ext_vector_type(4)));
typedef float f32x4 __attribute__((ext_vector_type(4)));

#define DIM 768
#define NE 4
#define NH 12
#define HD 64
#define MLP_HID 3072
#define FC1_OUT 5376
#define FC2_IN 3840
#define CAP 512
#define LOG2E 1.44269504088896340736f

__device__ __forceinline__ void async_copy16(const void* g, void* l) {
  __builtin_amdgcn_global_load_lds((const __attribute__((address_space(1))) void*)g,
                                   (__attribute__((address_space(3))) void*)l, 16, 0, 0);
}

// sigmoid-form tanh-GELU: gelu(v) = v * rcp(1 + exp2(v*(c1 + c2*v^2)))
// max abs dev from exact-erf gelu ~7e-4 -- invisible at bf16.
__device__ __forceinline__ float gelu_f(float v) {
  float v2 = v * v;
  float t = v * fmaf(-0.102944f, v2, -2.302208f);
  float e = exp2f(t);
  return v * __builtin_amdgcn_rcpf(1.0f + e);
}

// ---------------- fused: weight cast (blocks 0..2047, vectorized) + router softmax (2048..4095) ----------------
__global__ __launch_bounds__(256) void cast_router_kernel(const float* __restrict__ w1,
                                                          const float* __restrict__ w2,
                                                          bf16_t* __restrict__ w1b,
                                                          bf16_t* __restrict__ w2b,
                                                          const float* __restrict__ x,
                                                          const float* __restrict__ wr,
                                                          float* __restrict__ probs) {
  if (blockIdx.x < 2048) {
    const int V1 = FC1_OUT * DIM / 4;       // 1032192 float4's
    const int V2 = 1536 * FC2_IN / 4;       // 1474560 float4's
    for (int i = blockIdx.x * 256 + threadIdx.x; i < V1 + V2; i += 2048 * 256) {
      if (i < V1) {
        float4 v = ((const float4*)w1)[i];
        bf16x4 pk = {(bf16_t)v.x, (bf16_t)v.y, (bf16_t)v.z, (bf16_t)v.w};
        *(bf16x4*)(w1b + i * 4) = pk;
      } else {
        int k = i - V1;
        float4 v = ((const float4*)w2)[k];
        bf16x4 pk = {(bf16_t)v.x, (bf16_t)v.y, (bf16_t)v.z, (bf16_t)v.w};
        *(bf16x4*)(w2b + k * 4) = pk;
      }
    }
    return;
  }
  int t = (blockIdx.x - 2048) * 4 + (threadIdx.x >> 6);
  int l = threadIdx.x & 63;
  const float* xr = x + (size_t)t * DIM;
  float a0 = 0.f, a1 = 0.f, a2 = 0.f, a3 = 0.f;
#pragma unroll
  for (int i = 0; i < 12; i++) {
    int d = l + i * 64;
    float xv = xr[d];
    a0 += xv * wr[d];
    a1 += xv * wr[DIM + d];
    a2 += xv * wr[2 * DIM + d];
    a3 += xv * wr[3 * DIM + d];
  }
#pragma unroll
  for (int off = 32; off > 0; off >>= 1) {
    a0 += __shfl_down(a0, off);
    a1 += __shfl_down(a1, off);
    a2 += __shfl_down(a2, off);
    a3 += __shfl_down(a3, off);
  }
  if (l == 0) {
    float m = fmaxf(fmaxf(a0, a1), fmaxf(a2, a3));
    float e0 = expf(a0 - m), e1 = expf(a1 - m), e2 = expf(a2 - m), e3 = expf(a3 - m);
    float inv = 1.0f / (e0 + e1 + e2 + e3);
    int b = t >> 10, n = t & 1023;
    probs[(b * NE + 0) * 1024 + n] = e0 * inv;
    probs[(b * NE + 1) * 1024 + n] = e1 * inv;
    probs[(b * NE + 2) * 1024 + n] = e2 * inv;
    probs[(b * NE + 3) * 1024 + n] = e3 * inv;
  }
}

// ---------------- exact top-k membership via ranking ----------------
__global__ __launch_bounds__(256) void rank_kernel(const float* __restrict__ probs,
                                                   float* __restrict__ gate_tok) {
  int be = blockIdx.y;
  __shared__ float p[1024];
  for (int i = threadIdx.x; i < 1024; i += 256) p[i] = probs[be * 1024 + i];
  __syncthreads();
  int n = blockIdx.x * 256 + threadIdx.x;
  float pn = p[n];
  int rank = 0;
  for (int j = 0; j < 1024; j++) {
    float pj = p[j];
    rank += (pj > pn) || (pj == pn && j < n);
  }
  int b = be >> 2, e = be & 3;
  gate_tok[(size_t)((b << 10) + n) * 4 + e] = (rank < CAP) ? pn : 0.0f;
}

// ---------------- LayerNorm + segment-count scaling -> bf16 (lane-contiguous, vectorized) ----------------
// lane l handles d in [12l, 12l+12); segment boundaries 96/192/384/768 are multiples of 12
// so cf is uniform per lane.
__global__ __launch_bounds__(256) void ln_kernel(const float* __restrict__ x,
                                                 const float* __restrict__ gamma,
                                                 const float* __restrict__ beta,
                                                 const float* __restrict__ gate_tok,
                                                 bf16_t* __restrict__ ytil,
                                                 float* __restrict__ cntf,
                                                 float* __restrict__ g4) {
  int t = blockIdx.x * 4 + (threadIdx.x >> 6);
  int l = threadIdx.x & 63;
  float4 gg = ((const float4*)gate_tok)[t];
  float s0 = (gg.x > 0.f) ? 1.f : 0.f;
  float s1 = (gg.y > 0.f) ? 1.f : 0.f;
  float s2 = (gg.z > 0.f) ? 1.f : 0.f;
  float s3 = (gg.w > 0.f) ? 1.f : 0.f;
  float c3 = s3, c2 = c3 + s2, c1 = c2 + s1, c0 = c1 + s0;
  if (l == 0) {
    cntf[t] = c0;
    float4 G;
    G.x = gg.x + gg.y + gg.z + gg.w;
    G.y = gg.y + gg.z + gg.w;
    G.z = gg.z + gg.w;
    G.w = gg.w;
    ((float4*)g4)[t] = G;
  }
  const float* xr = x + (size_t)t * DIM + l * 12;
  float4 v4[3];
#pragma unroll
  for (int j = 0; j < 3; j++) v4[j] = *(const float4*)(xr + j * 4);
  float s = 0.f, sq = 0.f;
#pragma unroll
  for (int j = 0; j < 3; j++) {
    s += v4[j].x + v4[j].y + v4[j].z + v4[j].w;
    sq += v4[j].x * v4[j].x + v4[j].y * v4[j].y + v4[j].z * v4[j].z + v4[j].w * v4[j].w;
  }
#pragma unroll
  for (int off = 1; off < 64; off <<= 1) {
    s += __shfl_xor(s, off);
    sq += __shfl_xor(sq, off);
  }
  float mean = s * (1.0f / DIM);
  float var = sq * (1.0f / DIM) - mean * mean;
  float rs = rsqrtf(var + 1e-6f);
  int d0 = l * 12;
  float cf = (d0 < 96) ? c0 : (d0 < 192) ? c1 : (d0 < 384) ? c2 : c3;
  bf16_t* yo = ytil + (size_t)t * DIM + d0;
#pragma unroll
  for (int j = 0; j < 3; j++) {
    float4 gv = *(const float4*)(gamma + d0 + j * 4);
    float4 bv = *(const float4*)(beta + d0 + j * 4);
    bf16x4 pk;
    pk[0] = (bf16_t)(((v4[j].x - mean) * rs * gv.x + bv.x) * cf);
    pk[1] = (bf16_t)(((v4[j].y - mean) * rs * gv.y + bv.y) * cf);
    pk[2] = (bf16_t)(((v4[j].z - mean) * rs * gv.z + bv.z) * cf);
    pk[3] = (bf16_t)(((v4[j].w - mean) * rs * gv.w + bv.w) * cf);
    *(bf16x4*)(yo + j * 4) = pk;
  }
}

// ---------------- FC1 dense: [8192,5376] = ytil @ w1^T + cnt*b1; epilogue gelu / qkv split ----------------
// Q is pre-scaled by 0.125*log2e so attention scores are directly in log2 units.
// vtb (transposed V) stores packed 4x bf16 across r (n consecutive) -> 4x fewer scattered stores.
__global__ __launch_bounds__(256, 4) void fc1_kernel(const bf16_t* __restrict__ ytil,
                                                     const bf16_t* __restrict__ w1b,
                                                     const float* __restrict__ b1,
                                                     const float* __restrict__ cntf,
                                                     bf16_t* __restrict__ y2b,
                                                     bf16_t* __restrict__ qb,
                                                     bf16_t* __restrict__ kb,
                                                     bf16_t* __restrict__ vtb) {
  const int bid = blockIdx.x;
  const int xcd = bid & 7, j = bid >> 3;      // j in 0..335
  const int mt = xcd * 8 + (j & 7);           // 0..63 (fast within XCD)
  const int nt = j >> 3;                      // 0..41 (slow)
  const int tid = threadIdx.x;
  const int w = tid >> 6, l = tid & 63;
  const int lq = l >> 4, lr = l & 15;

  __shared__ __align__(16) bf16_t lA[128 * 64];
  __shared__ __align__(16) bf16_t lB[128 * 64];

  f32x4 acc[4][4] = {};
  const int mwave = (w & 1) * 64, nwave = (w >> 1) * 64;
  const int crow = l >> 3;
  const int cbg = (l & 7) ^ (crow & 7);

  for (int k0 = 0; k0 < DIM; k0 += 64) {
#pragma unroll
    for (int i = 0; i < 4; i++) {
      int c = w * 4 + i;
      int row = c * 8 + crow;
      async_copy16(ytil + (size_t)(mt * 128 + row) * DIM + k0 + cbg * 8, lA + c * 512);
      async_copy16(w1b + (size_t)(nt * 128 + row) * DIM + k0 + cbg * 8, lB + c * 512);
    }
    __syncthreads();
#pragma unroll
    for (int ks = 0; ks < 2; ks++) {
      const int cbA = ((ks * 4 + lq) ^ (lr & 7)) * 8;
      bf16x8 af[4], bfr[4];
#pragma unroll
      for (int mi = 0; mi < 4; mi++)
        af[mi] = *(const bf16x8*)(lA + (mwave + mi * 16 + lr) * 64 + cbA);
#pragma unroll
      for (int ni = 0; ni < 4; ni++)
        bfr[ni] = *(const bf16x8*)(lB + (nwave + ni * 16 + lr) * 64 + cbA);
#pragma unroll
      for (int mi = 0; mi < 4; mi++)
#pragma unroll
        for (int ni = 0; ni < 4; ni++)
          acc[mi][ni] = __builtin_amdgcn_mfma_f32_16x16x32_bf16(af[mi], bfr[ni], acc[mi][ni], 0, 0, 0);
    }
    __syncthreads();
  }

#pragma unroll
  for (int mi = 0; mi < 4; mi++) {
    int row0 = mt * 128 + mwave + mi * 16 + lq * 4;
    float cnt[4];
#pragma unroll
    for (int r = 0; r < 4; r++) cnt[r] = cntf[row0 + r];
#pragma unroll
    for (int ni = 0; ni < 4; ni++) {
      int col = nt * 128 + nwave + ni * 16 + lr;
      float bias = b1[col];
      if (col < MLP_HID) {
#pragma unroll
        for (int r = 0; r < 4; r++) {
          float v = acc[mi][ni][r] + cnt[r] * bias;
          y2b[(size_t)(row0 + r) * FC2_IN + col] = (bf16_t)gelu_f(v);
        }
      } else {
        int part = col - MLP_HID;
        int comp = (part >= 1536) ? 2 : (part >= 768) ? 1 : 0;
        int rem = part - comp * 768;
        int hh = rem >> 6, d = rem & 63;
        int b = row0 >> 10, n0 = row0 & 1023;
        size_t base = (size_t)(b * NH + hh);
        if (comp == 2) {
          bf16x4 pk;
#pragma unroll
          for (int r = 0; r < 4; r++)
            pk[r] = (bf16_t)(acc[mi][ni][r] + cnt[r] * bias);
          *(bf16x4*)(vtb + (base * HD + d) * 1024 + n0) = pk;
        } else {
#pragma unroll
          for (int r = 0; r < 4; r++) {
            float v = acc[mi][ni][r] + cnt[r] * bias;
            if (comp == 0) qb[(base * 1024 + n0 + r) * HD + d] = (bf16_t)(v * (0.125f * LOG2E));
            else           kb[(base * 1024 + n0 + r) * HD + d] = (bf16_t)v;
          }
        }
      }
    }
  }
}

// ---------------- flash attention, no-max softmax, 128-row Q tiles, XCD-local K/V ----------------
__global__ __launch_bounds__(256) void attn_kernel(const bf16_t* __restrict__ qb,
                                                   const bf16_t* __restrict__ kb,
                                                   const bf16_t* __restrict__ vtb,
                                                   bf16_t* __restrict__ y2b) {
  const int bid = blockIdx.x;                 // 0..767
  const int xcd = bid & 7, j = bid >> 3;      // j 0..95
  const int bh = xcd * 12 + (j >> 3);         // all 8 q-blocks of a head on one XCD
  const int qt = j & 7;                       // 128-row q tile
  const int tid = threadIdx.x;
  const int w = tid >> 6, l = tid & 63, lq = l >> 4, lr = l & 15;

  __shared__ __align__(16) bf16_t lK[64 * 64];
  __shared__ __align__(16) bf16_t lV[64 * 64];
  __shared__ __align__(16) bf16_t lP[4][16 * 72];

  const bf16_t* qbase = qb + (size_t)bh * 1024 * HD;
  const bf16_t* kbase = kb + (size_t)bh * 1024 * HD;
  const bf16_t* vbase = vtb + (size_t)bh * HD * 1024;

  bf16x8 qf[2][2];
#pragma unroll
  for (int h = 0; h < 2; h++) {
    int qrow = qt * 128 + h * 64 + w * 16 + lr;
#pragma unroll
    for (int s = 0; s < 2; s++)
      qf[h][s] = *(const bf16x8*)(qbase + (size_t)qrow * HD + s * 32 + lq * 8);
  }

  f32x4 oacc[2][4] = {};
  float psum[2][4] = {};

  const int crow = l >> 3;
  const int cbg = (l & 7) ^ (crow & 7);

  for (int kt = 0; kt < 16; kt++) {
#pragma unroll
    for (int i = 0; i < 2; i++) {
      int c = w * 2 + i;
      int row = c * 8 + crow;
      async_copy16(kbase + (size_t)(kt * 64 + row) * HD + cbg * 8, lK + c * 512);
      async_copy16(vbase + (size_t)row * 1024 + kt * 64 + cbg * 8, lV + c * 512);
    }
    __syncthreads();

#pragma unroll
    for (int h = 0; h < 2; h++) {
      f32x4 sacc[4] = {};
#pragma unroll
      for (int s = 0; s < 2; s++) {
        const int cb = ((s * 4 + lq) ^ (lr & 7)) * 8;
#pragma unroll
        for (int kbq = 0; kbq < 4; kbq++) {
          bf16x8 kf = *(const bf16x8*)(lK + (kbq * 16 + lr) * 64 + cb);
          sacc[kbq] = __builtin_amdgcn_mfma_f32_16x16x32_bf16(qf[h][s], kf, sacc[kbq], 0, 0, 0);
        }
      }

      // pv = exp2(score); per-lane partial row sums; wave-private lP slab (reused per half)
#pragma unroll
      for (int kbq = 0; kbq < 4; kbq++)
#pragma unroll
        for (int r = 0; r < 4; r++) {
          float pv = exp2f(sacc[kbq][r]);
          psum[h][r] += pv;
          lP[w][(lq * 4 + r) * 72 + kbq * 16 + lr] = (bf16_t)pv;
        }

      bf16x8 pf[2];
#pragma unroll
      for (int s = 0; s < 2; s++)
        pf[s] = *(const bf16x8*)(&lP[w][lr * 72 + s * 32 + lq * 8]);

#pragma unroll
      for (int s = 0; s < 2; s++) {
        const int cb = ((s * 4 + lq) ^ (lr & 7)) * 8;
#pragma unroll
        for (int nb = 0; nb < 4; nb++) {
          bf16x8 vf = *(const bf16x8*)(lV + (nb * 16 + lr) * 64 + cb);
          oacc[h][nb] = __builtin_amdgcn_mfma_f32_16x16x32_bf16(pf[s], vf, oacc[h][nb], 0, 0, 0);
        }
      }
    }
    __syncthreads();
  }

  int b = bh / NH, hh = bh % NH;
#pragma unroll
  for (int h = 0; h < 2; h++) {
#pragma unroll
    for (int off = 1; off < 16; off <<= 1)
#pragma unroll
      for (int r = 0; r < 4; r++) psum[h][r] += __shfl_xor(psum[h][r], off);
    float rinv[4];
#pragma unroll
    for (int r = 0; r < 4; r++) rinv[r] = 1.0f / psum[h][r];
#pragma unroll
    for (int nb = 0; nb < 4; nb++)
#pragma unroll
      for (int r = 0; r < 4; r++) {
        float v = oacc[h][nb][r] * rinv[r];
        int tok = qt * 128 + h * 64 + w * 16 + lq * 4 + r;
        y2b[((size_t)(b * 1024 + tok)) * FC2_IN + MLP_HID + hh * HD + nb * 16 + lr] = (bf16_t)v;
      }
  }
}

// ---------------- FC2 dense fused: out = x + Sum_halves G_seg(col) * (y2 @ w2^T + b2) ----------------
__global__ __launch_bounds__(256, 4) void fc2_kernel(const bf16_t* __restrict__ y2b,
                                                     const bf16_t* __restrict__ w2b,
                                                     const float* __restrict__ b2,
                                                     const float* __restrict__ g4,
                                                     const float* __restrict__ x,
                                                     float* __restrict__ out) {
  const int bid = blockIdx.x;
  const int xcd = bid & 7, j = bid >> 3;
  const int mt = xcd * 8 + j / 12;
  const int ct = j % 12;
  const int tid = threadIdx.x;
  const int w = tid >> 6, l = tid & 63;
  const int lq = l >> 4, lr = l & 15;

  __shared__ __align__(16) bf16_t lA[128 * 64];
  __shared__ __align__(16) bf16_t lB[128 * 64];

  f32x4 acc[2][4][2] = {};
  const int mwave = (w & 1) * 64, nwave = (w >> 1) * 32;
  const int crow = l >> 3;
  const int cbg = (l & 7) ^ (crow & 7);

  for (int k0 = 0; k0 < FC2_IN; k0 += 64) {
#pragma unroll
    for (int i = 0; i < 4; i++) {
      int c = w * 4 + i;
      int row = c * 8 + crow;
      async_copy16(y2b + (size_t)(mt * 128 + row) * FC2_IN + k0 + cbg * 8, lA + c * 512);
      int grow = ((row >> 6) * 768) + ct * 64 + (row & 63);
      async_copy16(w2b + (size_t)grow * FC2_IN + k0 + cbg * 8, lB + c * 512);
    }
    __syncthreads();
#pragma unroll
    for (int ks = 0; ks < 2; ks++) {
      const int cbA = ((ks * 4 + lq) ^ (lr & 7)) * 8;
      bf16x8 af[4], bfr[2][2];
#pragma unroll
      for (int mi = 0; mi < 4; mi++)
        af[mi] = *(const bf16x8*)(lA + (mwave + mi * 16 + lr) * 64 + cbA);
#pragma unroll
      for (int h = 0; h < 2; h++)
#pragma unroll
        for (int ni = 0; ni < 2; ni++)
          bfr[h][ni] = *(const bf16x8*)(lB + (h * 64 + nwave + ni * 16 + lr) * 64 + cbA);
#pragma unroll
      for (int h = 0; h < 2; h++)
#pragma unroll
        for (int mi = 0; mi < 4; mi++)
#pragma unroll
          for (int ni = 0; ni < 2; ni++)
            acc[h][mi][ni] = __builtin_amdgcn_mfma_f32_16x16x32_bf16(af[mi], bfr[h][ni], acc[h][mi][ni], 0, 0, 0);
    }
    __syncthreads();
  }

#pragma unroll
  for (int mi = 0; mi < 4; mi++) {
    int row0 = mt * 128 + mwave + mi * 16 + lq * 4;
    float4 G[4];
#pragma unroll
    for (int r = 0; r < 4; r++) G[r] = ((const float4*)g4)[row0 + r];
#pragma unroll
    for (int ni = 0; ni < 2; ni++) {
      int col = ct * 64 + nwave + ni * 16 + lr;
      float b20 = b2[col], b21 = b2[768 + col];
#pragma unroll
      for (int r = 0; r < 4; r++) {
        float gw = (col < 96) ? G[r].x : (col < 192) ? G[r].y : (col < 384) ? G[r].z : G[r].w;
        float o = (acc[0][mi][ni][r] + b20) + (acc[1][mi][ni][r] + b21);
        size_t idx = (size_t)(row0 + r) * DIM + col;
        out[idx] = x[idx] + gw * o;
      }
    }
  }
}

extern "C" void kernel_launch(void* const* d_in, const int* in_sizes, int n_in,
                              void* d_out, int out_size, void* d_ws, size_t ws_size,
                              hipStream_t stream) {
  const float* x     = (const float*)d_in[0];
  const float* wr    = (const float*)d_in[1];
  const float* gamma = (const float*)d_in[2];
  const float* beta  = (const float*)d_in[3];
  const float* w1    = (const float*)d_in[4];
  const float* b1    = (const float*)d_in[5];
  const float* w2    = (const float*)d_in[6];
  const float* b2    = (const float*)d_in[7];
  float* out = (float*)d_out;

  char* ws = (char*)d_ws;
  float*  probs    = (float*)(ws + 0);            // 131072
  float*  gate_tok = (float*)(ws + 131072);       // 131072
  float*  cntf     = (float*)(ws + 262144);       // 32768
  float*  g4       = (float*)(ws + 294912);       // 131072
  bf16_t* w1b      = (bf16_t*)(ws + 425984);      // 8257536
  bf16_t* w2b      = (bf16_t*)(ws + 8683520);     // 11796480
  bf16_t* ytil     = (bf16_t*)(ws + 20480000);    // 12582912
  bf16_t* y2b      = (bf16_t*)(ws + 33062912);    // 62914560
  bf16_t* qb       = (bf16_t*)(ws + 95977472);    // 12582912
  bf16_t* kb       = (bf16_t*)(ws + 108560384);   // 12582912
  bf16_t* vtb      = (bf16_t*)(ws + 121143296);   // 12582912

  cast_router_kernel<<<4096, 256, 0, stream>>>(w1, w2, w1b, w2b, x, wr, probs);
  rank_kernel<<<dim3(4, 32), 256, 0, stream>>>(probs, gate_tok);
  ln_kernel<<<2048, 256, 0, stream>>>(x, gamma, beta, gate_tok, ytil, cntf, g4);
  fc1_kernel<<<2688, 256, 0, stream>>>(ytil, w1b, b1, cntf, y2b, qb, kb, vtb);
  attn_kernel<<<768, 256, 0, stream>>>(qb, kb, vtb, y2b);
  fc2_kernel<<<768, 256, 0, stream>>>(y2b, w2b, b2, g4, x, out);
}